// Round 7
// baseline (120.946 us; speedup 1.0000x reference)
//
#include <hip/hip_runtime.h>
#include <hip/hip_fp16.h>

// Problem constants
#define BB 512      // batch
#define FF 1024     // features (= K of GEMM, = NK*KD)
#define NK 64       // num kernels
#define KD 16       // kernel dim

typedef __attribute__((ext_vector_type(4))) float f32x4;
typedef __attribute__((ext_vector_type(8))) _Float16 half8;

__device__ __forceinline__ unsigned short f16_bits(float f) {
    __half h = __float2half(f);   // RNE
    return *reinterpret_cast<unsigned short*>(&h);
}

// ---------------------------------------------------------------------------
// Prep: blocks 0..255  : T 64x64 transpose tiles -> Tf [n][k] f16.
//       Tile mapping is XCD-aligned with the consumer GEMM block (n0idx's
//       XCD = n0idx>>1 = b&7) so Tf stays in the consumer's L2.
//       blocks 256..383: x -> xf f16. Block 256 zeroes the barrier counter.
// ---------------------------------------------------------------------------
__global__ __launch_bounds__(256) void md_prep_kernel(
    const float* __restrict__ x, const float* __restrict__ T,
    unsigned short* __restrict__ xf, unsigned short* __restrict__ Tf,
    int* __restrict__ bar) {
    const int b = blockIdx.x;
    const int t = threadIdx.x;
    if (b < 256) {
        __shared__ float tile[64][65];
        const int n0 = (2 * (b & 7) + ((b >> 3) & 1)) * 64;
        const int k0 = (b >> 4) * 64;
        #pragma unroll
        for (int rr = 0; rr < 4; ++rr) {
            const int kk = rr * 16 + (t >> 4);
            const float4 v = *(const float4*)&T[(size_t)(k0 + kk) * FF + n0 + (t & 15) * 4];
            tile[kk][(t & 15) * 4 + 0] = v.x; tile[kk][(t & 15) * 4 + 1] = v.y;
            tile[kk][(t & 15) * 4 + 2] = v.z; tile[kk][(t & 15) * 4 + 3] = v.w;
        }
        __syncthreads();
        #pragma unroll
        for (int rr = 0; rr < 4; ++rr) {
            const int nl = rr * 16 + (t >> 4);
            const int kl = (t & 15) * 4;
            ushort4 h;
            h.x = f16_bits(tile[kl + 0][nl]);
            h.y = f16_bits(tile[kl + 1][nl]);
            h.z = f16_bits(tile[kl + 2][nl]);
            h.w = f16_bits(tile[kl + 3][nl]);
            *(ushort4*)&Tf[(size_t)(n0 + nl) * FF + k0 + kl] = h;
        }
    } else {
        if (b == 256 && t == 0) *bar = 0;
        const int base = (b - 256) * 256 + t;
        #pragma unroll
        for (int s = 0; s < 4; ++s) {
            const int idx = s * 32768 + base;    // float4 index
            const float4 v = *(const float4*)&x[(size_t)idx * 4];
            ushort4 h;
            h.x = f16_bits(v.x); h.y = f16_bits(v.y);
            h.z = f16_bits(v.z); h.w = f16_bits(v.w);
            *(ushort4*)&xf[(size_t)idx * 4] = h;
        }
    }
}

// ---------------------------------------------------------------------------
// Fused GEMM + device-barrier + symmetric pairwise. 256 blocks x 512 thr
// (all trivially co-resident: 29KB LDS, 1 block/CU nominal).
//   GEMM phase : f16 MFMA, BM=32 BN=64 BK=64 dbuf (R6-verified structure);
//                nt determined by b&7 so each XCD produces kblk [8xc,8xc+8)
//                locally. Blocks 0,1 zero `out`.
//   barrier    : release fence -> atomic arrival -> spin -> acquire fence.
//   pairwise   : 9 units/block of (k, upper-tri 64x64 tile pair), k range
//                XCD-matched to the GEMM production. atomicAdd row+col sums.
// ---------------------------------------------------------------------------
__global__ __launch_bounds__(512) void md_gemm_pair_kernel(
    const unsigned short* __restrict__ xf, const unsigned short* __restrict__ Tf,
    float* __restrict__ M2, float* __restrict__ out, int* __restrict__ bar) {
    union Sh {
        unsigned short glds[2][6144];               // GEMM: 24 KB
        struct {                                    // pairwise: ~29 KB
            float Mi[64][20];
            float Mj[64][16];
            float et[64][65];
            float pr[8][64];
            float pc[8][64];
        } pw;
    };
    __shared__ Sh sh;

    const int t = threadIdx.x, w = t >> 6, l = t & 63;
    const int b = blockIdx.x, xc = b & 7, s = b >> 3;

    // ===================== Phase 1: GEMM =====================
    {
        const int nt = xc * 2 + (s & 1);           // XCD-local n-tile
        const int mt = s >> 1;                     // 0..15

        if (b < 2) {
            const float4 z = make_float4(0.f, 0.f, 0.f, 0.f);
            #pragma unroll
            for (int q = 0; q < 8; ++q)
                *(float4*)&out[(size_t)(b * 4096 + q * 512 + t) * 4] = z;
        }

        // staging: LDS gets (row, c) <- global (row, c ^ (row&7)); row&7 == l>>3.
        const int col16s = (l & 7) ^ (l >> 3);
        const unsigned short* gA = xf + ((size_t)mt * 32 + (w & 3) * 8 + (l >> 3)) * FF + col16s * 8;
        const unsigned short* gB = Tf + ((size_t)nt * 64 + w * 8 + (l >> 3)) * FF + col16s * 8;
        const int ldsA = (w & 3) * 8 * 64;
        const int ldsB = 2048 + w * 8 * 64;

        const int lrow = l & 15, lkg = l >> 4;
        const int ar = (w >> 2) * 16 + lrow;       // A row 0..31
        const int br = (w & 3) * 16 + lrow;        // B row 0..63
        const int swa = ar & 7, swb = br & 7;

        f32x4 acc = {};

        if (w < 4)
            __builtin_amdgcn_global_load_lds(
                (const __attribute__((address_space(1))) void*)gA,
                (__attribute__((address_space(3))) void*)&sh.glds[0][ldsA], 16, 0, 0);
        __builtin_amdgcn_global_load_lds(
            (const __attribute__((address_space(1))) void*)gB,
            (__attribute__((address_space(3))) void*)&sh.glds[0][ldsB], 16, 0, 0);
        __syncthreads();

        int buf = 0;
        for (int it = 0; it < 16; ++it) {
            if (it < 15) {
                const int kt = (it + 1) * 64;
                if (w < 4)
                    __builtin_amdgcn_global_load_lds(
                        (const __attribute__((address_space(1))) void*)(gA + kt),
                        (__attribute__((address_space(3))) void*)&sh.glds[buf ^ 1][ldsA], 16, 0, 0);
                __builtin_amdgcn_global_load_lds(
                    (const __attribute__((address_space(1))) void*)(gB + kt),
                    (__attribute__((address_space(3))) void*)&sh.glds[buf ^ 1][ldsB], 16, 0, 0);
            }
            const unsigned short* L = sh.glds[buf];
            #pragma unroll
            for (int ks = 0; ks < 2; ++ks) {
                const int cb = ks * 4 + lkg;
                const half8 a = *(const half8*)&L[ar * 64 + (cb ^ swa) * 8];
                const half8 v = *(const half8*)&L[2048 + br * 64 + (cb ^ swb) * 8];
                acc = __builtin_amdgcn_mfma_f32_16x16x32_f16(a, v, acc, 0, 0, 0);
            }
            __syncthreads();
            buf ^= 1;
        }

        // C/D (m89): col = lane&15, row = (lane>>4)*4 + reg
        const int kblk = nt * 4 + (w & 3);         // in [8xc, 8xc+8)
        const int rowb = mt * 32 + (w >> 2) * 16 + lkg * 4;
        #pragma unroll
        for (int rg = 0; rg < 4; ++rg)
            M2[((size_t)kblk * BB + rowb + rg) * KD + lrow] = acc[rg];
    }

    // ===================== Device barrier =====================
    __threadfence();                 // release: M2 + out-zero visible
    __syncthreads();
    if (t == 0) {
        atomicAdd(bar, 1);
        while (__hip_atomic_load(bar, __ATOMIC_RELAXED, __HIP_MEMORY_SCOPE_AGENT) < 256)
            __builtin_amdgcn_s_sleep(8);
    }
    __syncthreads();
    __threadfence();                 // acquire: discard stale cached lines

    // ===================== Phase 2: symmetric pairwise =====================
    // XCD-local units: k in [8xc, 8xc+8), 36 tile-pairs, 9 units per block.
    const int cu = b >> 3;           // 0..31 within XCD
    for (int u = 0; u < 9; ++u) {
        const int beta = cu * 9 + u;             // 0..287
        const int k = 8 * xc + (beta & 7);
        int p = beta >> 3;                       // 0..35
        int it = 0;
        while (p >= 8 - it) { p -= 8 - it; ++it; }
        const int jt = it + p;
        const bool diag = (it == jt);

        __syncthreads();   // protect LDS reuse across units
        {
            const int tt = t & 255;
            const int row = tt >> 2, dg = (tt & 3) * 4;
            const float* tile = (t < 256)
                ? M2 + ((size_t)k * BB + it * 64) * KD
                : M2 + ((size_t)k * BB + jt * 64) * KD;
            const float4 a = *(const float4*)&tile[tt * 4];
            if (t < 256) *(float4*)&sh.pw.Mi[row][dg] = a;
            else         *(float4*)&sh.pw.Mj[row][dg] = a;
        }
        __syncthreads();

        const int i = t & 63;
        const int wv = t >> 6;              // 0..7 -> j-chunk of 8

        float mi[16];
        #pragma unroll
        for (int dg = 0; dg < 4; ++dg) {
            const float4 v = *(const float4*)&sh.pw.Mi[i][dg * 4];
            mi[dg * 4 + 0] = v.x; mi[dg * 4 + 1] = v.y;
            mi[dg * 4 + 2] = v.z; mi[dg * 4 + 3] = v.w;
        }

        float row_acc = 0.0f;
        #pragma unroll
        for (int jj = 0; jj < 8; ++jj) {
            const int j = wv * 8 + jj;      // wave-uniform -> broadcast reads
            const float4* mj = (const float4*)&sh.pw.Mj[j][0];
            const float4 v0 = mj[0], v1 = mj[1], v2 = mj[2], v3 = mj[3];
            float p0 = (fabsf(mi[0] - v0.x) + fabsf(mi[1] - v0.y)) +
                       (fabsf(mi[2] - v0.z) + fabsf(mi[3] - v0.w));
            float p1 = (fabsf(mi[4] - v1.x) + fabsf(mi[5] - v1.y)) +
                       (fabsf(mi[6] - v1.z) + fabsf(mi[7] - v1.w));
            float p2 = (fabsf(mi[8] - v2.x) + fabsf(mi[9] - v2.y)) +
                       (fabsf(mi[10] - v2.z) + fabsf(mi[11] - v2.w));
            float p3 = (fabsf(mi[12] - v3.x) + fabsf(mi[13] - v3.y)) +
                       (fabsf(mi[14] - v3.z) + fabsf(mi[15] - v3.w));
            const float e = __expf(-((p0 + p1) + (p2 + p3)));
            row_acc += e;
            sh.pw.et[i][j] = e;             // banks (i+j)%32 -> 2-way, free
        }
        sh.pw.pr[wv][i] = row_acc;
        __syncthreads();

        if (!diag) {
            const int j = t & 63;
            const int chunk = t >> 6;       // 0..7 -> ii-chunk of 8
            float col_acc = 0.0f;
            #pragma unroll
            for (int ii = 0; ii < 8; ++ii)
                col_acc += sh.pw.et[chunk * 8 + ii][j];
            sh.pw.pc[chunk][j] = col_acc;
        }
        __syncthreads();

        if (t < 64) {
            float r = ((sh.pw.pr[0][t] + sh.pw.pr[1][t]) + (sh.pw.pr[2][t] + sh.pw.pr[3][t])) +
                      ((sh.pw.pr[4][t] + sh.pw.pr[5][t]) + (sh.pw.pr[6][t] + sh.pw.pr[7][t])) -
                      (diag ? 1.0f : 0.0f);
            atomicAdd(&out[(size_t)(it * 64 + t) * NK + k], r);
        } else if (t < 128 && !diag) {
            const int j = t - 64;
            float c = ((sh.pw.pc[0][j] + sh.pw.pc[1][j]) + (sh.pw.pc[2][j] + sh.pw.pc[3][j])) +
                      ((sh.pw.pc[4][j] + sh.pw.pc[5][j]) + (sh.pw.pc[6][j] + sh.pw.pc[7][j]));
            atomicAdd(&out[(size_t)(jt * 64 + j) * NK + k], c);
        }
    }
}

extern "C" void kernel_launch(void* const* d_in, const int* in_sizes, int n_in,
                              void* d_out, int out_size, void* d_ws, size_t ws_size,
                              hipStream_t stream) {
    const float* x = (const float*)d_in[0];   // [512, 1024] f32
    const float* T = (const float*)d_in[1];   // [1024, 1024] f32
    float* out = (float*)d_out;               // [512, 64] f32

    unsigned short* xf = (unsigned short*)d_ws;         // 512x1024 f16
    unsigned short* Tf = xf + (size_t)BB * FF;          // 1024x1024 f16 [n][k]
    float* M2 = (float*)(Tf + (size_t)FF * FF);         // [64][512][16] f32
    int* bar = (int*)(M2 + (size_t)NK * BB * KD);       // barrier counter

    md_prep_kernel<<<384, 256, 0, stream>>>(x, T, xf, Tf, bar);
    md_gemm_pair_kernel<<<dim3(256), 512, 0, stream>>>(xf, Tf, M2, out, bar);
}

// Round 8
// 36.377 us; speedup vs baseline: 3.3248x; 3.3248x over previous
//
#include <hip/hip_runtime.h>
#include <hip/hip_fp16.h>

// Problem constants
#define BB 512      // batch
#define FF 1024     // features (= K of GEMM, = NK*KD)
#define NK 64       // num kernels
#define KD 16       // kernel dim

typedef __attribute__((ext_vector_type(4))) float f32x4;
typedef __attribute__((ext_vector_type(8))) _Float16 half8;

__device__ __forceinline__ unsigned short f16_bits(float f) {
    __half h = __float2half(f);   // RNE
    return *reinterpret_cast<unsigned short*>(&h);
}

// ---------------------------------------------------------------------------
// Prep (R6/R7-verified): blocks 0..255: T 64x64 transpose tiles -> Tf [n][k]
// f16, XCD-aligned with consumer GEMM (n panel [128xc,128xc+128) produced on
// xcd xc). blocks 256..383: x -> xf f16.
// ---------------------------------------------------------------------------
__global__ __launch_bounds__(256) void md_prep_kernel(
    const float* __restrict__ x, const float* __restrict__ T,
    unsigned short* __restrict__ xf, unsigned short* __restrict__ Tf) {
    const int b = blockIdx.x;
    const int t = threadIdx.x;
    if (b < 256) {
        __shared__ float tile[64][65];
        const int n0 = (2 * (b & 7) + ((b >> 3) & 1)) * 64;
        const int k0 = (b >> 4) * 64;
        #pragma unroll
        for (int rr = 0; rr < 4; ++rr) {
            const int kk = rr * 16 + (t >> 4);
            const float4 v = *(const float4*)&T[(size_t)(k0 + kk) * FF + n0 + (t & 15) * 4];
            tile[kk][(t & 15) * 4 + 0] = v.x; tile[kk][(t & 15) * 4 + 1] = v.y;
            tile[kk][(t & 15) * 4 + 2] = v.z; tile[kk][(t & 15) * 4 + 3] = v.w;
        }
        __syncthreads();
        #pragma unroll
        for (int rr = 0; rr < 4; ++rr) {
            const int nl = rr * 16 + (t >> 4);
            const int kl = (t & 15) * 4;
            ushort4 h;
            h.x = f16_bits(tile[kl + 0][nl]);
            h.y = f16_bits(tile[kl + 1][nl]);
            h.z = f16_bits(tile[kl + 2][nl]);
            h.w = f16_bits(tile[kl + 3][nl]);
            *(ushort4*)&Tf[(size_t)(n0 + nl) * FF + k0 + kl] = h;
        }
    } else {
        const int base = (b - 256) * 256 + t;
        #pragma unroll
        for (int s = 0; s < 4; ++s) {
            const int idx = s * 32768 + base;    // float4 index
            const float4 v = *(const float4*)&x[(size_t)idx * 4];
            ushort4 h;
            h.x = f16_bits(v.x); h.y = f16_bits(v.y);
            h.z = f16_bits(v.z); h.w = f16_bits(v.w);
            *(ushort4*)&xf[(size_t)idx * 4] = h;
        }
    }
}

// ---------------------------------------------------------------------------
// MFMA GEMM, f16 single product, full-K. BM=32, BN=32, BK=64.
// grid 512 blocks (2 blocks/CU for latency overlap), 256 thr (4 waves),
// 16 KB LDS dbuf. nt = 4*xcd + .. keeps B panels XCD-local to prep.
// Wave w: stages A/B rows [8w,8w+8); computes one 16x16 output frag.
// Swizzle: LDS (row,c16) <- global (row, c16^(row&7)); read c16 = cb^(row&7).
// Output M2[kblk][512][16] f32. Blocks 0..3 also zero `out`.
// ---------------------------------------------------------------------------
__global__ __launch_bounds__(256) void md_mfma_kernel(
    const unsigned short* __restrict__ xf, const unsigned short* __restrict__ Tf,
    float* __restrict__ M2, float* __restrict__ out) {
    // per buf (ushort offsets): A[32][64] @0, B[32][64] @2048 = 8 KB
    __shared__ __align__(16) unsigned short lds[2][4096];

    const int t = threadIdx.x, w = t >> 6, l = t & 63;
    const int b = blockIdx.x, xc = b & 7, r = b >> 3;
    const int nt = xc * 4 + (r & 3);           // 0..31 (32-col n-tile)
    const int mt = r >> 2;                     // 0..15 (32-row m-tile)

    // zero `out` (128 KB) by blocks 0..3
    if (b < 4) {
        const float4 z = make_float4(0.f, 0.f, 0.f, 0.f);
        #pragma unroll
        for (int q = 0; q < 8; ++q)
            *(float4*)&out[(size_t)(b * 2048 + q * 256 + t) * 4] = z;
    }

    const int col16s = (l & 7) ^ (l >> 3);
    const unsigned short* gA = xf + ((size_t)mt * 32 + w * 8 + (l >> 3)) * FF + col16s * 8;
    const unsigned short* gB = Tf + ((size_t)nt * 32 + w * 8 + (l >> 3)) * FF + col16s * 8;
    const int ldsA = w * 8 * 64;
    const int ldsB = 2048 + w * 8 * 64;

    const int lrow = l & 15, lkg = l >> 4;
    const int ar = (w >> 1) * 16 + lrow;       // A row 0..31
    const int br = (w & 1) * 16 + lrow;        // B row 0..31
    const int swa = ar & 7, swb = br & 7;

    f32x4 acc = {};

    __builtin_amdgcn_global_load_lds(
        (const __attribute__((address_space(1))) void*)gA,
        (__attribute__((address_space(3))) void*)&lds[0][ldsA], 16, 0, 0);
    __builtin_amdgcn_global_load_lds(
        (const __attribute__((address_space(1))) void*)gB,
        (__attribute__((address_space(3))) void*)&lds[0][ldsB], 16, 0, 0);
    __syncthreads();

    int buf = 0;
    for (int it = 0; it < 16; ++it) {
        if (it < 15) {
            const int kt = (it + 1) * 64;
            __builtin_amdgcn_global_load_lds(
                (const __attribute__((address_space(1))) void*)(gA + kt),
                (__attribute__((address_space(3))) void*)&lds[buf ^ 1][ldsA], 16, 0, 0);
            __builtin_amdgcn_global_load_lds(
                (const __attribute__((address_space(1))) void*)(gB + kt),
                (__attribute__((address_space(3))) void*)&lds[buf ^ 1][ldsB], 16, 0, 0);
        }
        const unsigned short* L = lds[buf];
        #pragma unroll
        for (int ks = 0; ks < 2; ++ks) {
            const int cb = ks * 4 + lkg;               // k-chunk 0..7
            const half8 a = *(const half8*)&L[ar * 64 + (cb ^ swa) * 8];
            const half8 v = *(const half8*)&L[2048 + br * 64 + (cb ^ swb) * 8];
            acc = __builtin_amdgcn_mfma_f32_16x16x32_f16(a, v, acc, 0, 0, 0);
        }
        __syncthreads();
        buf ^= 1;
    }

    // C/D (m89): col = lane&15, row = (lane>>4)*4 + reg
    const int kblk = nt * 2 + (w & 1);         // 0..63
    const int rowb = mt * 32 + (w >> 1) * 16 + lkg * 4;
    #pragma unroll
    for (int rg = 0; rg < 4; ++rg)
        M2[((size_t)kblk * BB + rowb + rg) * KD + lrow] = acc[rg];
}

// ---------------------------------------------------------------------------
// Symmetric pairwise: M2 [kblk][512][16], tiles contiguous. 36 upper-tri
// tile-pairs x 64 k = 2304 blocks x 256 thr. LDS 22.3 KB -> ~7 blocks/CU.
// mi is read directly from global (L2-hot, coalesced) - no Mi stage.
// ---------------------------------------------------------------------------
__global__ __launch_bounds__(256) void md_pairwise_sym_kernel(
    const float* __restrict__ M2, float* __restrict__ out) {
    __shared__ float Mj[64][16];
    __shared__ float et[64][65];
    __shared__ float part_row[4][64];
    __shared__ float part_col[4][64];

    const int bx = blockIdx.x;
    const int k = bx & 63;
    int p = bx >> 6;
    int it = 0;
    while (p >= 8 - it) { p -= 8 - it; ++it; }
    const int jt = it + p;
    const bool diag = (it == jt);
    const int t = threadIdx.x;

    const float* tileI = M2 + ((size_t)k * BB + it * 64) * KD;
    const float* tileJ = M2 + ((size_t)k * BB + jt * 64) * KD;

    // stage Mj (4 KB, one float4/thread)
    {
        const int row = t >> 2, dg = (t & 3) * 4;
        *(float4*)&Mj[row][dg] = *(const float4*)&tileJ[t * 4];
    }

    const int i = t & 63;
    const int wv = t >> 6;

    // mi from global: lane i reads row i of tileI (wave covers 4 KB contig)
    float mi[16];
    #pragma unroll
    for (int dg = 0; dg < 4; ++dg) {
        const float4 v = *(const float4*)&tileI[i * KD + dg * 4];
        mi[dg * 4 + 0] = v.x; mi[dg * 4 + 1] = v.y;
        mi[dg * 4 + 2] = v.z; mi[dg * 4 + 3] = v.w;
    }
    __syncthreads();

    float row_acc = 0.0f;
    #pragma unroll 4
    for (int jj = 0; jj < 16; ++jj) {
        const int j = wv * 16 + jj;      // wave-uniform -> broadcast reads
        const float4* mj = (const float4*)&Mj[j][0];
        const float4 v0 = mj[0], v1 = mj[1], v2 = mj[2], v3 = mj[3];
        float p0 = (fabsf(mi[0] - v0.x) + fabsf(mi[1] - v0.y)) +
                   (fabsf(mi[2] - v0.z) + fabsf(mi[3] - v0.w));
        float p1 = (fabsf(mi[4] - v1.x) + fabsf(mi[5] - v1.y)) +
                   (fabsf(mi[6] - v1.z) + fabsf(mi[7] - v1.w));
        float p2 = (fabsf(mi[8] - v2.x) + fabsf(mi[9] - v2.y)) +
                   (fabsf(mi[10] - v2.z) + fabsf(mi[11] - v2.w));
        float p3 = (fabsf(mi[12] - v3.x) + fabsf(mi[13] - v3.y)) +
                   (fabsf(mi[14] - v3.z) + fabsf(mi[15] - v3.w));
        const float e = __expf(-((p0 + p1) + (p2 + p3)));
        row_acc += e;
        et[i][j] = e;                    // banks (i+j)%32 -> conflict-free
    }
    part_row[wv][i] = row_acc;
    __syncthreads();

    if (!diag) {
        const int j = t & 63;
        const int chunk = t >> 6;
        float col_acc = 0.0f;
        #pragma unroll
        for (int ii = 0; ii < 16; ++ii)
            col_acc += et[chunk * 16 + ii][j];
        part_col[chunk][j] = col_acc;
    }
    __syncthreads();

    if (t < 64) {
        float r = ((part_row[0][t] + part_row[1][t]) +
                   (part_row[2][t] + part_row[3][t])) - (diag ? 1.0f : 0.0f);
        atomicAdd(&out[(size_t)(it * 64 + t) * NK + k], r);
    } else if (t < 128 && !diag) {
        const int j = t - 64;
        float c = (part_col[0][j] + part_col[1][j]) +
                  (part_col[2][j] + part_col[3][j]);
        atomicAdd(&out[(size_t)(jt * 64 + j) * NK + k], c);
    }
}

extern "C" void kernel_launch(void* const* d_in, const int* in_sizes, int n_in,
                              void* d_out, int out_size, void* d_ws, size_t ws_size,
                              hipStream_t stream) {
    const float* x = (const float*)d_in[0];   // [512, 1024] f32
    const float* T = (const float*)d_in[1];   // [1024, 1024] f32
    float* out = (float*)d_out;               // [512, 64] f32

    unsigned short* xf = (unsigned short*)d_ws;         // 512x1024 f16
    unsigned short* Tf = xf + (size_t)BB * FF;          // 1024x1024 f16 [n][k]
    float* M2 = (float*)(Tf + (size_t)FF * FF);         // [64][512][16] f32

    md_prep_kernel<<<384, 256, 0, stream>>>(x, T, xf, Tf);
    md_mfma_kernel<<<dim3(512), 256, 0, stream>>>(xf, Tf, M2, out);
    md_pairwise_sym_kernel<<<dim3(36 * 64), 256, 0, stream>>>(M2, out);
}